// Round 8
// baseline (292.865 us; speedup 1.0000x reference)
//
#include <hip/hip_runtime.h>
#include <math.h>

// Problem constants
#define M_ROWS 32768   // 32*32*32 positions
#define DIMS   256
#define KCODES 4096
#define NTILE  32      // column tiles of 128
#define EPS_C  0.5f    // collection window vs block-row-min (hh err max ~0.1)
#define EPS_R  1.25f   // refine window (covers EPS_C + f16 key rounding)

// ws layout (float units) — ~2.4 MB
#define WS_CH     0          // 4096*256 halves = 524288 floats (codebook hi f16)
#define WS_V2     524288     // 32768 floats ||v||^2 (fp32-exact)
#define WS_C2     557056     // 4096  floats ||c||^2
#define WS_COLKEY 561152     // 4096  u32 f32-bits colmin (entropy)
#define WS_TOKEN  565248     // 32768 u32 tokens
#define WS_PART   598016     // 8192 floats per-block mse partials

// d_out scratch (overwritten by vq_gather at the end):
//   floats [0, 4194304)        : Vh    = 32768*256 f16
//   floats [4194304, 8388608)  : candG = 32768 rows * 32 tiles * 4 u32

typedef _Float16 half8 __attribute__((ext_vector_type(8)));
typedef _Float16 half4 __attribute__((ext_vector_type(4)));
typedef float floatx4 __attribute__((ext_vector_type(4)));

__device__ inline void glds16(const void* g, void* l) {
  __builtin_amdgcn_global_load_lds(
      (const __attribute__((address_space(1))) void*)g,
      (__attribute__((address_space(3))) void*)l, 16, 0, 0);
}

// ---------------------------------------------------------------------------
// prep: f16-hi conversion of V (-> d_out scratch) and CB (-> ws), exact fp32
// norms, plus colkey init (replaces memset).
__global__ __launch_bounds__(256) void vq_prep(const float* __restrict__ V,
                                               const float* __restrict__ CB,
                                               float* __restrict__ ws,
                                               float* __restrict__ outbuf) {
  if (blockIdx.x < 16)
    ((unsigned*)(ws + WS_COLKEY))[blockIdx.x * 256 + threadIdx.x] = 0xFFFFFFFFu;
  int w = threadIdx.x >> 6, lane = threadIdx.x & 63;
  int row = blockIdx.x * 4 + w;
  const float* src;
  _Float16* dst;
  float* nrm;
  if (row < M_ROWS) {
    src = V + (size_t)row * DIMS;
    dst = (_Float16*)outbuf + (size_t)row * DIMS;
    nrm = ws + WS_V2 + row;
  } else {
    int r = row - M_ROWS;
    src = CB + (size_t)r * DIMS;
    dst = (_Float16*)(ws + WS_CH) + (size_t)r * DIMS;
    nrm = ws + WS_C2 + r;
  }
  float4 v = ((const float4*)src)[lane];
  half4 h;
  h[0] = (_Float16)v.x; h[1] = (_Float16)v.y;
  h[2] = (_Float16)v.z; h[3] = (_Float16)v.w;
  *(half4*)(dst + lane * 4) = h;
  float s = v.x * v.x + v.y * v.y + v.z * v.z + v.w * v.w;
  #pragma unroll
  for (int off = 32; off > 0; off >>= 1) s += __shfl_down(s, off, 64);
  if (lane == 0) *nrm = s;
}

// ---------------------------------------------------------------------------
// hh GEMM. v9: 256x128 tile, 8 waves x (64x64) — round-7 retry with the
// register cap REMOVED. Round 7's __launch_bounds__(512,4) forced a 128-reg
// cap (acc alone = 64 AGPR) -> spills (WRITE_SIZE 37->182 MB) masked the
// tile experiment entirely. LDS (59.5 KB) caps us at 2 blocks/CU anyway, so
// (512,2) gives the allocator 256 regs/wave: natural use ~64 AGPR + ~70 arch,
// no spill, same occupancy. Tile rationale unchanged: LDS read amplification
// sum(Mw+Nw)/(BM+BN) = 3.0 -> 2.67, ds_read_b128 count -33%, barriers halved.
// Schedule = v6 syncthreads-dbuf (proven best of 3 schedule variants).
// Keeps: v6 reduce-scatter rowmin, atomic-free partials, compare-only phase 2.
__global__ __launch_bounds__(512, 2) void vq_hh(const _Float16* __restrict__ Vh,
                                                const _Float16* __restrict__ Ch,
                                                const float* __restrict__ wsv2,
                                                const float* __restrict__ wsc2,
                                                unsigned* __restrict__ candG,
                                                unsigned* __restrict__ colkey) {
  __shared__ alignas(16) _Float16 Ah[2][256 * 32];   // 32 KB (dbuf)
  __shared__ alignas(16) _Float16 Bh[2][128 * 32];   // 16 KB (dbuf)
  __shared__ float v2s[256];
  __shared__ float c2s[128];
  __shared__ float rowminW[2][256];                  // per-wn partial row mins
  __shared__ float rowminF[256];
  __shared__ unsigned cnt[256];
  __shared__ unsigned candL[256][4];
  __shared__ float colM[4][128];                     // per-wm partial col mins

  const int t = threadIdx.x;                  // 0..511
  const int lane = t & 63, w = t >> 6;        // 8 waves
  const int wm = w & 3, wn = w >> 2;          // wave grid 4x2, each 64x64
  const int q = lane >> 4, c = lane & 15;
  const int rt = blockIdx.x >> 5, ct = blockIdx.x & 31;
  const int rowBase = rt * 256, colBase = ct * 128;

  if (t < 256)      { v2s[t] = wsv2[rowBase + t]; cnt[t] = 0u; }
  else if (t < 384) c2s[t - 256] = wsc2[colBase + (t - 256)];
  ((unsigned*)candL)[t] = 0xFFFFFFFFu;        // 1024 entries, 2 per thread
  ((unsigned*)candL)[t + 512] = 0xFFFFFFFFu;

  floatx4 acc[4][4];
  #pragma unroll
  for (int i = 0; i < 4; ++i)
    #pragma unroll
    for (int j = 0; j < 4; ++j) acc[i][j] = (floatx4){0.f, 0.f, 0.f, 0.f};

  // staging per chunk: A = 1024 16B-chunks (2/thread), B = 512 (1/thread).
  // XOR swizzle: slot (r, jslot) holds k-chunk jslot^((r>>1)&3) of row r.
  const int r0 = t >> 2,        j0 = (t & 3) ^ ((r0 >> 1) & 3);
  const int s1 = t + 512;
  const int r1 = s1 >> 2,       j1 = (s1 & 3) ^ ((r1 >> 1) & 3);
  const _Float16* gA0 = Vh + (size_t)(rowBase + r0) * DIMS + j0 * 8;
  const _Float16* gA1 = Vh + (size_t)(rowBase + r1) * DIMS + j1 * 8;
  const _Float16* gB  = Ch + (size_t)(colBase + r0) * DIMS + j0 * 8;
  // wave-uniform LDS bases (buffer strides: A 16384 B, B 8192 B)
  char* lA0 = (char*)Ah + w * 1024;
  char* lA1 = (char*)Ah + 8192 + w * 1024;
  char* lB  = (char*)Bh + w * 1024;
  const int sw = (c >> 1) & 3;                // frag-read swizzle term

  // prologue: stage chunk 0 into buffer 0
  glds16(gA0, lA0); glds16(gA1, lA1); glds16(gB, lB);
  gA0 += 32; gA1 += 32; gB += 32;
  __syncthreads();   // drains prologue stage + covers LDS init

  #pragma unroll
  for (int kc = 0; kc < 8; ++kc) {
    const int cur = kc & 1;
    if (kc < 7) {                             // issue stage(k+1) FIRST
      const int nbA = (cur ^ 1) * 16384;
      const int nbB = (cur ^ 1) * 8192;
      glds16(gA0, lA0 + nbA); glds16(gA1, lA1 + nbA); glds16(gB, lB + nbB);
      gA0 += 32; gA1 += 32; gB += 32;
    }
    const _Float16* Ab = Ah[cur];
    const _Float16* Bb = Bh[cur];
    half8 a[4];
    #pragma unroll
    for (int f = 0; f < 4; ++f) {
      int ra = wm * 64 + f * 16 + c;
      a[f] = *(const half8*)(Ab + ra * 32 + (q ^ sw) * 8);
    }
    #pragma unroll
    for (int fj = 0; fj < 4; ++fj) {
      int rb = wn * 64 + fj * 16 + c;
      half8 b = *(const half8*)(Bb + rb * 32 + (q ^ sw) * 8);
      #pragma unroll
      for (int fi = 0; fi < 4; ++fi)
        acc[fi][fj] = __builtin_amdgcn_mfma_f32_16x16x32_f16(a[fi], b, acc[fi][fj], 0, 0, 0);
    }
    // single barrier per chunk: drains stage(k+1) after compute overlapped it,
    // and guarantees all waves finished reading buf[cur] before restaging.
    __syncthreads();
  }

  // ---- phase 1: in-place distance transform + halving rowmin + colmin -----
  float cm[4] = {3.4e38f, 3.4e38f, 3.4e38f, 3.4e38f};
  float rv[16];                               // per-lane partial row mins
  float c2v[4];
  #pragma unroll
  for (int fj = 0; fj < 4; ++fj) c2v[fj] = c2s[wn * 64 + fj * 16 + c];
  #pragma unroll
  for (int fi = 0; fi < 4; ++fi) {
    #pragma unroll
    for (int r = 0; r < 4; ++r) {
      int ml = wm * 64 + fi * 16 + q * 4 + r;
      float vv = v2s[ml];
      float dmin = 3.4e38f;
      #pragma unroll
      for (int fj = 0; fj < 4; ++fj) {
        float d = vv + c2v[fj] - 2.f * acc[fi][fj][r];
        acc[fi][fj][r] = d;
        cm[fj] = fminf(cm[fj], d);
        dmin = fminf(dmin, d);
      }
      rv[fi * 4 + r] = dmin;
    }
  }
  // reduce-scatter min across the 16-lane c-group: 15 shfls, no dependencies
  // between the shfls within a step. After 4 steps lane c owns row brev4(c).
  {
    const int b0 = c & 1;
    #pragma unroll
    for (int k = 0; k < 8; ++k) {
      float send = b0 ? rv[k] : rv[k + 8];
      float recv = __shfl_xor(send, 1, 64);
      rv[k] = fminf(b0 ? rv[k + 8] : rv[k], recv);
    }
    const int b1 = (c >> 1) & 1;
    #pragma unroll
    for (int k = 0; k < 4; ++k) {
      float send = b1 ? rv[k] : rv[k + 4];
      float recv = __shfl_xor(send, 2, 64);
      rv[k] = fminf(b1 ? rv[k + 4] : rv[k], recv);
    }
    const int b2 = (c >> 2) & 1;
    #pragma unroll
    for (int k = 0; k < 2; ++k) {
      float send = b2 ? rv[k] : rv[k + 2];
      float recv = __shfl_xor(send, 4, 64);
      rv[k] = fminf(b2 ? rv[k + 2] : rv[k], recv);
    }
    const int b3 = (c >> 3) & 1;
    {
      float send = b3 ? rv[0] : rv[1];
      float recv = __shfl_xor(send, 8, 64);
      rv[0] = fminf(b3 ? rv[1] : rv[0], recv);
    }
    const int kf = (b0 << 3) | (b1 << 2) | (b2 << 1) | b3;
    rowminW[wn][wm * 64 + (kf >> 2) * 16 + q * 4 + (kf & 3)] = rv[0];
  }
  // colmin: lanes sharing a column differ only in q -> xor 16, 32
  #pragma unroll
  for (int fj = 0; fj < 4; ++fj) {
    cm[fj] = fminf(cm[fj], __shfl_xor(cm[fj], 16, 64));
    cm[fj] = fminf(cm[fj], __shfl_xor(cm[fj], 32, 64));
  }
  if (lane < 16) {
    #pragma unroll
    for (int fj = 0; fj < 4; ++fj) colM[wm][wn * 64 + fj * 16 + c] = cm[fj];
  }
  __syncthreads();

  // fold the 2 per-wn partials into the final row min
  if (t < 256)
    rowminF[t] = fminf(rowminW[0][t], rowminW[1][t]);
  __syncthreads();

  // ---- phase 2: collect candidates within rowmin + EPS_C (compare-only) ----
  #pragma unroll
  for (int fi = 0; fi < 4; ++fi) {
    #pragma unroll
    for (int r = 0; r < 4; ++r) {
      int ml = wm * 64 + fi * 16 + q * 4 + r;
      float thresh = rowminF[ml] + EPS_C;
      #pragma unroll
      for (int fj = 0; fj < 4; ++fj) {
        float d = acc[fi][fj][r];
        if (d <= thresh) {
          unsigned pos = atomicAdd(&cnt[ml], 1u);
          if (pos < 4) {
            unsigned short hb = __builtin_bit_cast(unsigned short, (_Float16)d);
            int nl = wn * 64 + fj * 16 + c;
            candL[ml][pos] = ((unsigned)hb << 16) | (unsigned)(colBase + nl);
          }
        }
      }
    }
  }
  __syncthreads();
  if (t < 256)
    *(uint4*)(candG + ((size_t)(rowBase + t) * NTILE + ct) * 4) = *(uint4*)candL[t];
  if (t < 128) {
    float cv = fminf(fminf(colM[0][t], colM[1][t]),
                     fminf(colM[2][t], colM[3][t]));
    atomicMin(&colkey[colBase + t], __float_as_uint(cv));
  }
}

// ---------------------------------------------------------------------------
// refine: per row pick best f16 key; fp64-verify all candidates within EPS_R
// (rare). Separate kernel: must finish reading candG (in d_out) before
// vq_gather overwrites d_out. One wave per row.
__global__ __launch_bounds__(256) void vq_refine(const float* __restrict__ V,
                                                 const float* __restrict__ CB,
                                                 const unsigned* __restrict__ candG,
                                                 unsigned* __restrict__ token) {
  int w = threadIdx.x >> 6, lane = threadIdx.x & 63;
  int row = blockIdx.x * 4 + w;
  const unsigned* cg = candG + (size_t)row * (NTILE * 4);
  unsigned e0 = cg[lane], e1 = cg[lane + 64];
  unsigned m = e0 < e1 ? e0 : e1;
  #pragma unroll
  for (int off = 1; off < 64; off <<= 1) {
    unsigned o = __shfl_xor(m, off, 64);
    m = (o < m) ? o : m;
  }
  float bestv = (float)__builtin_bit_cast(_Float16, (unsigned short)(m >> 16));
  float v0k = (float)__builtin_bit_cast(_Float16, (unsigned short)(e0 >> 16));
  float v1k = (float)__builtin_bit_cast(_Float16, (unsigned short)(e1 >> 16));
  // empty slots (0xFFFF) decode to NaN -> compare false -> excluded
  unsigned long long mask0 = __ballot(v0k <= bestv + EPS_R);
  unsigned long long mask1 = __ballot(v1k <= bestv + EPS_R);
  int tok = (int)(m & 0xFFFFu);
  if (__popcll(mask0) + __popcll(mask1) > 1) {
    float4 x = ((const float4*)(V + (size_t)row * DIMS))[lane];
    double bd = 1e300; int bi = 0x7FFFFFFF;
    #pragma unroll
    for (int h = 0; h < 2; ++h) {
      unsigned long long mask = h ? mask1 : mask0;
      unsigned ee = h ? e1 : e0;
      while (mask) {
        int l = __ffsll((unsigned long long)mask) - 1;
        mask &= mask - 1;
        int idx = (int)(__shfl(ee, l, 64) & 0xFFFFu);
        float4 cv = ((const float4*)(CB + (size_t)idx * DIMS))[lane];
        double dx = (double)cv.x - (double)x.x;
        double dy = (double)cv.y - (double)x.y;
        double dz = (double)cv.z - (double)x.z;
        double dw = (double)cv.w - (double)x.w;
        double s = dx * dx + dy * dy + dz * dz + dw * dw;
        #pragma unroll
        for (int off = 1; off < 64; off <<= 1) s += __shfl_xor(s, off, 64);
        if (s < bd || (s == bd && idx < bi)) { bd = s; bi = idx; }
      }
    }
    tok = bi;
  }
  if (lane == 0) token[row] = (unsigned)tok;
}

// ---------------------------------------------------------------------------
// gather: out = x + (e - x); per-block mse partial via PLAIN STORE (round 4's
// __threadfence per block forced an L2 wb/inv per block -> 268 us stall).
__global__ __launch_bounds__(256) void vq_gather(const float* __restrict__ V,
                                                 const float* __restrict__ CB,
                                                 const unsigned* __restrict__ token,
                                                 float* __restrict__ ws,
                                                 float* __restrict__ out) {
  __shared__ float psum[4];
  int w = threadIdx.x >> 6, lane = threadIdx.x & 63;
  int row = blockIdx.x * 4 + w;
  int tok = (int)token[row];

  float4 e = *(const float4*)(CB + (size_t)tok * DIMS + lane * 4);
  float4 x = *(const float4*)(V + (size_t)row * DIMS + lane * 4);
  float dx = e.x - x.x, dy = e.y - x.y, dz = e.z - x.z, dw = e.w - x.w;
  float4 o;
  o.x = x.x + dx; o.y = x.y + dy; o.z = x.z + dz; o.w = x.w + dw;
  *(float4*)(out + (size_t)row * DIMS + lane * 4) = o;

  float s = dx * dx + dy * dy + dz * dz + dw * dw;
  #pragma unroll
  for (int off = 32; off > 0; off >>= 1) s += __shfl_down(s, off, 64);
  if (lane == 0) psum[w] = s;
  __syncthreads();
  if (threadIdx.x == 0)
    ws[WS_PART + blockIdx.x] = psum[0] + psum[1] + psum[2] + psum[3];
}

// ---------------------------------------------------------------------------
// final: sum 8192 mse partials + 4096 colmins, write loss. One block.
__global__ __launch_bounds__(256) void vq_final(const float* __restrict__ ws,
                                                float* __restrict__ out) {
  __shared__ float psum[4];
  float s = 0.f;
  for (int i = threadIdx.x; i < 8192; i += 256) s += ws[WS_PART + i];
  const unsigned* ck = (const unsigned*)(ws + WS_COLKEY);
  float cs = 0.f;
  for (int i = threadIdx.x; i < KCODES; i += 256) cs += __uint_as_float(ck[i]);
  float v = s * (1.25f / 8388608.f) + cs * (0.1f / 4096.f);
  #pragma unroll
  for (int off = 32; off > 0; off >>= 1) v += __shfl_down(v, off, 64);
  int w = threadIdx.x >> 6, lane = threadIdx.x & 63;
  if (lane == 0) psum[w] = v;
  __syncthreads();
  if (threadIdx.x == 0)
    out[8388608] = psum[0] + psum[1] + psum[2] + psum[3];
}

// ---------------------------------------------------------------------------
extern "C" void kernel_launch(void* const* d_in, const int* in_sizes, int n_in,
                              void* d_out, int out_size, void* d_ws, size_t ws_size,
                              hipStream_t stream) {
  const float* V  = (const float*)d_in[0];   // [32768, 256]
  const float* CB = (const float*)d_in[1];   // [4096, 256]
  float* out = (float*)d_out;                // 8388608 emb + 1 loss
  float* ws  = (float*)d_ws;

  _Float16* Vh     = (_Float16*)out;                 // scratch in d_out
  unsigned* candG  = (unsigned*)(out + 4194304);     // scratch in d_out (16 MB)
  unsigned* colkey = (unsigned*)(ws + WS_COLKEY);
  unsigned* token  = (unsigned*)(ws + WS_TOKEN);

  vq_prep<<<(M_ROWS + KCODES) / 4, 256, 0, stream>>>(V, CB, ws, out);
  vq_hh<<<4096, 512, 0, stream>>>(Vh, (const _Float16*)(ws + WS_CH),
                                  ws + WS_V2, ws + WS_C2, candG, colkey);
  vq_refine<<<M_ROWS / 4, 256, 0, stream>>>(V, CB, candG, token);
  vq_gather<<<M_ROWS / 4, 256, 0, stream>>>(V, CB, token, ws, out);
  vq_final<<<1, 256, 0, stream>>>(ws, out);
}

// Round 10
// 230.895 us; speedup vs baseline: 1.2684x; 1.2684x over previous
//
#include <hip/hip_runtime.h>
#include <math.h>

// Problem constants
#define M_ROWS 32768   // 32*32*32 positions
#define DIMS   256
#define KCODES 4096
#define NTILE  32      // column tiles of 128
#define EPS_C  0.5f    // collection window vs block-row-min (hh err max ~0.1)
#define EPS_R  1.25f   // refine window (covers EPS_C + f16 key rounding)

// ws layout (float units) — ~2.4 MB
#define WS_CH     0          // 4096*256 halves = 524288 floats (codebook hi f16)
#define WS_V2     524288     // 32768 floats ||v||^2 (fp32-exact)
#define WS_C2     557056     // 4096  floats ||c||^2
#define WS_COLKEY 561152     // 4096  u32 f32-bits colmin (entropy)
#define WS_TOKEN  565248     // 32768 u32 tokens
#define WS_PART   598016     // 8192 floats per-block mse partials

// d_out scratch (overwritten by vq_gather at the end):
//   floats [0, 4194304)        : Vh    = 32768*256 f16
//   floats [4194304, 8388608)  : candG = 32768 rows * 32 tiles * 4 u32

typedef _Float16 half8 __attribute__((ext_vector_type(8)));
typedef _Float16 half4 __attribute__((ext_vector_type(4)));
typedef float floatx4 __attribute__((ext_vector_type(4)));

__device__ inline void glds16(const void* g, void* l) {
  __builtin_amdgcn_global_load_lds(
      (const __attribute__((address_space(1))) void*)g,
      (__attribute__((address_space(3))) void*)l, 16, 0, 0);
}

// ---------------------------------------------------------------------------
// prep: f16-hi conversion of V (-> d_out scratch) and CB (-> ws), exact fp32
// norms, plus colkey init (replaces memset).
__global__ __launch_bounds__(256) void vq_prep(const float* __restrict__ V,
                                               const float* __restrict__ CB,
                                               float* __restrict__ ws,
                                               float* __restrict__ outbuf) {
  if (blockIdx.x < 16)
    ((unsigned*)(ws + WS_COLKEY))[blockIdx.x * 256 + threadIdx.x] = 0xFFFFFFFFu;
  int w = threadIdx.x >> 6, lane = threadIdx.x & 63;
  int row = blockIdx.x * 4 + w;
  const float* src;
  _Float16* dst;
  float* nrm;
  if (row < M_ROWS) {
    src = V + (size_t)row * DIMS;
    dst = (_Float16*)outbuf + (size_t)row * DIMS;
    nrm = ws + WS_V2 + row;
  } else {
    int r = row - M_ROWS;
    src = CB + (size_t)r * DIMS;
    dst = (_Float16*)(ws + WS_CH) + (size_t)r * DIMS;
    nrm = ws + WS_C2 + r;
  }
  float4 v = ((const float4*)src)[lane];
  half4 h;
  h[0] = (_Float16)v.x; h[1] = (_Float16)v.y;
  h[2] = (_Float16)v.z; h[3] = (_Float16)v.w;
  *(half4*)(dst + lane * 4) = h;
  float s = v.x * v.x + v.y * v.y + v.z * v.z + v.w * v.w;
  #pragma unroll
  for (int off = 32; off > 0; off >>= 1) s += __shfl_down(s, off, 64);
  if (lane == 0) *nrm = s;
}

// ---------------------------------------------------------------------------
// hh GEMM: 128x128 tile, 8 waves x (64x32). v10 = v6 (round-5 best, 135 us)
// + XCD-aware block swizzle. (Round-9 submission of this exact source hit an
// infra failure — resubmitted unchanged.) Tile/schedule design space closed:
// 256x128 (rounds 7/8) loses on occupancy (58->23%), counted-vmcnt (round 6)
// loses on lockstep (58->43%), dbuf prefetch (round 2) neutral.
// Swizzle: bid -> tile = (bid&7)*1024 + (bid>>3); XCD k owns rt in
// [k*32,(k+1)*32) -> per-XCD working set = 2MB A-panel + 2MB B = its 4MB L2,
// so staging hits L2 instead of L3/HBM and the per-chunk barrier drain
// shrinks. Bijective (8192 % 8 == 0).
// Keeps: v6 reduce-scatter rowmin, atomic-free partials, compare-only phase 2.
__global__ __launch_bounds__(512, 4) void vq_hh(const _Float16* __restrict__ Vh,
                                                const _Float16* __restrict__ Ch,
                                                const float* __restrict__ wsv2,
                                                const float* __restrict__ wsc2,
                                                unsigned* __restrict__ candG,
                                                unsigned* __restrict__ colkey) {
  __shared__ alignas(16) _Float16 Ah[2][128 * 32];   // 16 KB (dbuf)
  __shared__ alignas(16) _Float16 Bh[2][128 * 32];   // 16 KB (dbuf)
  __shared__ float v2s[128];
  __shared__ float c2s[128];
  __shared__ float rowminW[4][128];                  // per-wn partial row mins
  __shared__ float rowminF[128];
  __shared__ unsigned cnt[128];
  __shared__ unsigned candL[128][4];
  __shared__ float colM[2][128];

  const int t = threadIdx.x;                  // 0..511
  const int lane = t & 63, w = t >> 6;        // 8 waves
  const int wm = w & 1, wn = w >> 1;          // wave grid 2x4, each 64 rows x 32 cols
  const int q = lane >> 4, c = lane & 15;
  // XCD-aware swizzle: XCD k (bid%8) gets tiles [k*1024, (k+1)*1024) ->
  // rt in [k*32, (k+1)*32): A-panel stays resident in that XCD's L2.
  const int tile = (blockIdx.x & 7) * 1024 + (blockIdx.x >> 3);
  const int rt = tile >> 5, ct = tile & 31;
  const int rowBase = rt * 128, colBase = ct * 128;

  if (t < 128)      { v2s[t] = wsv2[rowBase + t]; cnt[t] = 0u; }
  else if (t < 256) c2s[t - 128] = wsc2[colBase + (t - 128)];
  ((unsigned*)candL)[t] = 0xFFFFFFFFu;        // 512 entries, one per thread

  floatx4 acc[4][2];
  #pragma unroll
  for (int i = 0; i < 4; ++i)
    #pragma unroll
    for (int j = 0; j < 2; ++j) acc[i][j] = (floatx4){0.f, 0.f, 0.f, 0.f};

  // staging: 512 16B-chunks per operand per buffer, 1 per thread per operand.
  // XOR swizzle: slot (r, jslot) holds k-chunk jslot^((r>>1)&3) of row r.
  const int r0 = t >> 2, j0 = (t & 3) ^ ((r0 >> 1) & 3);
  const _Float16* gA = Vh + (size_t)(rowBase + r0) * DIMS + j0 * 8;
  const _Float16* gB = Ch + (size_t)(colBase + r0) * DIMS + j0 * 8;
  // wave-uniform LDS bases (wave w covers bytes [w*1024, w*1024+1024))
  char* lA = (char*)Ah + w * 1024;
  char* lB = (char*)Bh + w * 1024;
  const int sw = (c >> 1) & 3;                // frag-read swizzle term

  // prologue: stage chunk 0 into buffer 0
  glds16(gA, lA); glds16(gB, lB);
  gA += 32; gB += 32;
  __syncthreads();   // drains prologue stage + covers LDS init

  #pragma unroll
  for (int kc = 0; kc < 8; ++kc) {
    const int cur = kc & 1;
    const int nb = (cur ^ 1) * 8192;          // byte offset of the other buffer
    if (kc < 7) {                             // issue stage(k+1) FIRST
      glds16(gA, lA + nb); glds16(gB, lB + nb);
      gA += 32; gB += 32;
    }
    const _Float16* Ab = Ah[cur];
    const _Float16* Bb = Bh[cur];
    half8 a[4], b[2];
    #pragma unroll
    for (int f = 0; f < 4; ++f) {
      int ra = wm * 64 + f * 16 + c;
      a[f] = *(const half8*)(Ab + ra * 32 + (q ^ sw) * 8);
    }
    #pragma unroll
    for (int f = 0; f < 2; ++f) {
      int rb = wn * 32 + f * 16 + c;
      b[f] = *(const half8*)(Bb + rb * 32 + (q ^ sw) * 8);
    }
    #pragma unroll
    for (int fi = 0; fi < 4; ++fi)
      #pragma unroll
      for (int fj = 0; fj < 2; ++fj)
        acc[fi][fj] = __builtin_amdgcn_mfma_f32_16x16x32_f16(a[fi], b[fj], acc[fi][fj], 0, 0, 0);
    __syncthreads();
  }

  // ---- phase 1: in-place distance transform + halving rowmin + colmin -----
  float cm0 = 3.4e38f, cm1 = 3.4e38f;
  float rv[16];                               // per-lane partial row mins
  const float c2v0 = c2s[wn * 32 + c];
  const float c2v1 = c2s[wn * 32 + 16 + c];
  #pragma unroll
  for (int fi = 0; fi < 4; ++fi) {
    #pragma unroll
    for (int r = 0; r < 4; ++r) {
      int ml = wm * 64 + fi * 16 + q * 4 + r;
      float vv = v2s[ml];
      float d0 = vv + c2v0 - 2.f * acc[fi][0][r];
      float d1 = vv + c2v1 - 2.f * acc[fi][1][r];
      acc[fi][0][r] = d0;
      acc[fi][1][r] = d1;
      cm0 = fminf(cm0, d0);
      cm1 = fminf(cm1, d1);
      rv[fi * 4 + r] = fminf(d0, d1);
    }
  }
  // reduce-scatter min across the 16-lane c-group: 15 shfls, no dependencies
  // between the shfls within a step. After 4 steps lane c owns row brev4(c).
  {
    const int b0 = c & 1;
    #pragma unroll
    for (int k = 0; k < 8; ++k) {
      float send = b0 ? rv[k] : rv[k + 8];
      float recv = __shfl_xor(send, 1, 64);
      rv[k] = fminf(b0 ? rv[k + 8] : rv[k], recv);
    }
    const int b1 = (c >> 1) & 1;
    #pragma unroll
    for (int k = 0; k < 4; ++k) {
      float send = b1 ? rv[k] : rv[k + 4];
      float recv = __shfl_xor(send, 2, 64);
      rv[k] = fminf(b1 ? rv[k + 4] : rv[k], recv);
    }
    const int b2 = (c >> 2) & 1;
    #pragma unroll
    for (int k = 0; k < 2; ++k) {
      float send = b2 ? rv[k] : rv[k + 2];
      float recv = __shfl_xor(send, 4, 64);
      rv[k] = fminf(b2 ? rv[k + 2] : rv[k], recv);
    }
    const int b3 = (c >> 3) & 1;
    {
      float send = b3 ? rv[0] : rv[1];
      float recv = __shfl_xor(send, 8, 64);
      rv[0] = fminf(b3 ? rv[1] : rv[0], recv);
    }
    const int kf = (b0 << 3) | (b1 << 2) | (b2 << 1) | b3;
    rowminW[wn][wm * 64 + (kf >> 2) * 16 + q * 4 + (kf & 3)] = rv[0];
  }
  // colmin: lanes sharing a column differ only in q -> xor 16, 32
  cm0 = fminf(cm0, __shfl_xor(cm0, 16, 64));
  cm0 = fminf(cm0, __shfl_xor(cm0, 32, 64));
  cm1 = fminf(cm1, __shfl_xor(cm1, 16, 64));
  cm1 = fminf(cm1, __shfl_xor(cm1, 32, 64));
  if (lane < 16) {
    colM[wm][wn * 32 + c]      = cm0;
    colM[wm][wn * 32 + 16 + c] = cm1;
  }
  __syncthreads();

  // fold the 4 per-wn partials into the final row min
  if (t < 128)
    rowminF[t] = fminf(fminf(rowminW[0][t], rowminW[1][t]),
                       fminf(rowminW[2][t], rowminW[3][t]));
  __syncthreads();

  // ---- phase 2: collect candidates within rowmin + EPS_C (compare-only) ----
  #pragma unroll
  for (int fi = 0; fi < 4; ++fi) {
    #pragma unroll
    for (int r = 0; r < 4; ++r) {
      int ml = wm * 64 + fi * 16 + q * 4 + r;
      float thresh = rowminF[ml] + EPS_C;
      #pragma unroll
      for (int fj = 0; fj < 2; ++fj) {
        float d = acc[fi][fj][r];
        if (d <= thresh) {
          unsigned pos = atomicAdd(&cnt[ml], 1u);
          if (pos < 4) {
            unsigned short hb = __builtin_bit_cast(unsigned short, (_Float16)d);
            int nl = wn * 32 + fj * 16 + c;
            candL[ml][pos] = ((unsigned)hb << 16) | (unsigned)(colBase + nl);
          }
        }
      }
    }
  }
  __syncthreads();
  if (t < 128) {
    *(uint4*)(candG + ((size_t)(rowBase + t) * NTILE + ct) * 4) = *(uint4*)candL[t];
    float cv = fminf(colM[0][t], colM[1][t]);
    atomicMin(&colkey[colBase + t], __float_as_uint(cv));
  }
}

// ---------------------------------------------------------------------------
// refine: per row pick best f16 key; fp64-verify all candidates within EPS_R
// (rare). Separate kernel: must finish reading candG (in d_out) before
// vq_gather overwrites d_out. One wave per row.
__global__ __launch_bounds__(256) void vq_refine(const float* __restrict__ V,
                                                 const float* __restrict__ CB,
                                                 const unsigned* __restrict__ candG,
                                                 unsigned* __restrict__ token) {
  int w = threadIdx.x >> 6, lane = threadIdx.x & 63;
  int row = blockIdx.x * 4 + w;
  const unsigned* cg = candG + (size_t)row * (NTILE * 4);
  unsigned e0 = cg[lane], e1 = cg[lane + 64];
  unsigned m = e0 < e1 ? e0 : e1;
  #pragma unroll
  for (int off = 1; off < 64; off <<= 1) {
    unsigned o = __shfl_xor(m, off, 64);
    m = (o < m) ? o : m;
  }
  float bestv = (float)__builtin_bit_cast(_Float16, (unsigned short)(m >> 16));
  float v0k = (float)__builtin_bit_cast(_Float16, (unsigned short)(e0 >> 16));
  float v1k = (float)__builtin_bit_cast(_Float16, (unsigned short)(e1 >> 16));
  // empty slots (0xFFFF) decode to NaN -> compare false -> excluded
  unsigned long long mask0 = __ballot(v0k <= bestv + EPS_R);
  unsigned long long mask1 = __ballot(v1k <= bestv + EPS_R);
  int tok = (int)(m & 0xFFFFu);
  if (__popcll(mask0) + __popcll(mask1) > 1) {
    float4 x = ((const float4*)(V + (size_t)row * DIMS))[lane];
    double bd = 1e300; int bi = 0x7FFFFFFF;
    #pragma unroll
    for (int h = 0; h < 2; ++h) {
      unsigned long long mask = h ? mask1 : mask0;
      unsigned ee = h ? e1 : e0;
      while (mask) {
        int l = __ffsll((unsigned long long)mask) - 1;
        mask &= mask - 1;
        int idx = (int)(__shfl(ee, l, 64) & 0xFFFFu);
        float4 cv = ((const float4*)(CB + (size_t)idx * DIMS))[lane];
        double dx = (double)cv.x - (double)x.x;
        double dy = (double)cv.y - (double)x.y;
        double dz = (double)cv.z - (double)x.z;
        double dw = (double)cv.w - (double)x.w;
        double s = dx * dx + dy * dy + dz * dz + dw * dw;
        #pragma unroll
        for (int off = 1; off < 64; off <<= 1) s += __shfl_xor(s, off, 64);
        if (s < bd || (s == bd && idx < bi)) { bd = s; bi = idx; }
      }
    }
    tok = bi;
  }
  if (lane == 0) token[row] = (unsigned)tok;
}

// ---------------------------------------------------------------------------
// gather: out = x + (e - x); per-block mse partial via PLAIN STORE (round 4's
// __threadfence per block forced an L2 wb/inv per block -> 268 us stall).
__global__ __launch_bounds__(256) void vq_gather(const float* __restrict__ V,
                                                 const float* __restrict__ CB,
                                                 const unsigned* __restrict__ token,
                                                 float* __restrict__ ws,
                                                 float* __restrict__ out) {
  __shared__ float psum[4];
  int w = threadIdx.x >> 6, lane = threadIdx.x & 63;
  int row = blockIdx.x * 4 + w;
  int tok = (int)token[row];

  float4 e = *(const float4*)(CB + (size_t)tok * DIMS + lane * 4);
  float4 x = *(const float4*)(V + (size_t)row * DIMS + lane * 4);
  float dx = e.x - x.x, dy = e.y - x.y, dz = e.z - x.z, dw = e.w - x.w;
  float4 o;
  o.x = x.x + dx; o.y = x.y + dy; o.z = x.z + dz; o.w = x.w + dw;
  *(float4*)(out + (size_t)row * DIMS + lane * 4) = o;

  float s = dx * dx + dy * dy + dz * dz + dw * dw;
  #pragma unroll
  for (int off = 32; off > 0; off >>= 1) s += __shfl_down(s, off, 64);
  if (lane == 0) psum[w] = s;
  __syncthreads();
  if (threadIdx.x == 0)
    ws[WS_PART + blockIdx.x] = psum[0] + psum[1] + psum[2] + psum[3];
}

// ---------------------------------------------------------------------------
// final: sum 8192 mse partials + 4096 colmins, write loss. One block.
__global__ __launch_bounds__(256) void vq_final(const float* __restrict__ ws,
                                                float* __restrict__ out) {
  __shared__ float psum[4];
  float s = 0.f;
  for (int i = threadIdx.x; i < 8192; i += 256) s += ws[WS_PART + i];
  const unsigned* ck = (const unsigned*)(ws + WS_COLKEY);
  float cs = 0.f;
  for (int i = threadIdx.x; i < KCODES; i += 256) cs += __uint_as_float(ck[i]);
  float v = s * (1.25f / 8388608.f) + cs * (0.1f / 4096.f);
  #pragma unroll
  for (int off = 32; off > 0; off >>= 1) v += __shfl_down(v, off, 64);
  int w = threadIdx.x >> 6, lane = threadIdx.x & 63;
  if (lane == 0) psum[w] = v;
  __syncthreads();
  if (threadIdx.x == 0)
    out[8388608] = psum[0] + psum[1] + psum[2] + psum[3];
}

// ---------------------------------------------------------------------------
extern "C" void kernel_launch(void* const* d_in, const int* in_sizes, int n_in,
                              void* d_out, int out_size, void* d_ws, size_t ws_size,
                              hipStream_t stream) {
  const float* V  = (const float*)d_in[0];   // [32768, 256]
  const float* CB = (const float*)d_in[1];   // [4096, 256]
  float* out = (float*)d_out;                // 8388608 emb + 1 loss
  float* ws  = (float*)d_ws;

  _Float16* Vh     = (_Float16*)out;                 // scratch in d_out
  unsigned* candG  = (unsigned*)(out + 4194304);     // scratch in d_out (16 MB)
  unsigned* colkey = (unsigned*)(ws + WS_COLKEY);
  unsigned* token  = (unsigned*)(ws + WS_TOKEN);

  vq_prep<<<(M_ROWS + KCODES) / 4, 256, 0, stream>>>(V, CB, ws, out);
  vq_hh<<<8192, 512, 0, stream>>>(Vh, (const _Float16*)(ws + WS_CH),
                                  ws + WS_V2, ws + WS_C2, candG, colkey);
  vq_refine<<<M_ROWS / 4, 256, 0, stream>>>(V, CB, candG, token);
  vq_gather<<<M_ROWS / 4, 256, 0, stream>>>(V, CB, token, ws, out);
  vq_final<<<1, 256, 0, stream>>>(ws, out);
}

// Round 12
// 217.319 us; speedup vs baseline: 1.3476x; 1.0625x over previous
//
#include <hip/hip_runtime.h>
#include <math.h>

// Problem constants
#define M_ROWS 32768   // 32*32*32 positions
#define DIMS   256
#define KCODES 4096
#define NTILE  32      // column tiles of 128
#define EPS_C  0.5f    // collection window vs block-row-min (hh err max ~0.1)
#define EPS_R  1.25f   // refine window (covers EPS_C + f16 key rounding)

// ws layout (float units) — ~2.4 MB
#define WS_CH     0          // 4096*256 halves = 524288 floats (codebook hi f16)
#define WS_V2     524288     // 32768 floats ||v||^2 (fp32-exact)
#define WS_C2     557056     // 4096  floats ||c||^2
#define WS_COLKEY 561152     // 4096  u32 f32-bits colmin (entropy)
#define WS_TOKEN  565248     // 32768 u32 tokens
#define WS_PART   598016     // 8192 floats per-block mse partials

// d_out scratch (overwritten by vq_gather at the end):
//   floats [0, 4194304)        : Vh    = 32768*256 f16
//   floats [4194304, 8388608)  : candG = 32768 rows * 32 tiles * 4 u32

typedef _Float16 half8 __attribute__((ext_vector_type(8)));
typedef _Float16 half4 __attribute__((ext_vector_type(4)));
typedef float floatx4 __attribute__((ext_vector_type(4)));

__device__ inline void glds16(const void* g, void* l) {
  __builtin_amdgcn_global_load_lds(
      (const __attribute__((address_space(1))) void*)g,
      (__attribute__((address_space(3))) void*)l, 16, 0, 0);
}

// ---------------------------------------------------------------------------
// prep: f16-hi conversion of V (-> d_out scratch) and CB (-> ws), exact fp32
// norms, plus colkey init (replaces memset).
__global__ __launch_bounds__(256) void vq_prep(const float* __restrict__ V,
                                               const float* __restrict__ CB,
                                               float* __restrict__ ws,
                                               float* __restrict__ outbuf) {
  if (blockIdx.x < 16)
    ((unsigned*)(ws + WS_COLKEY))[blockIdx.x * 256 + threadIdx.x] = 0xFFFFFFFFu;
  int w = threadIdx.x >> 6, lane = threadIdx.x & 63;
  int row = blockIdx.x * 4 + w;
  const float* src;
  _Float16* dst;
  float* nrm;
  if (row < M_ROWS) {
    src = V + (size_t)row * DIMS;
    dst = (_Float16*)outbuf + (size_t)row * DIMS;
    nrm = ws + WS_V2 + row;
  } else {
    int r = row - M_ROWS;
    src = CB + (size_t)r * DIMS;
    dst = (_Float16*)(ws + WS_CH) + (size_t)r * DIMS;
    nrm = ws + WS_C2 + r;
  }
  float4 v = ((const float4*)src)[lane];
  half4 h;
  h[0] = (_Float16)v.x; h[1] = (_Float16)v.y;
  h[2] = (_Float16)v.z; h[3] = (_Float16)v.w;
  *(half4*)(dst + lane * 4) = h;
  float s = v.x * v.x + v.y * v.y + v.z * v.z + v.w * v.w;
  #pragma unroll
  for (int off = 32; off > 0; off >>= 1) s += __shfl_down(s, off, 64);
  if (lane == 0) *nrm = s;
}

// ---------------------------------------------------------------------------
// hh GEMM: 128x128 tile, 8 waves x (64x32). v11 = v10 (round-10 best, 131 us:
// v6 structure + XCD swizzle, FETCH 67->16.6 MB) + colkey-atomic HOIST.
// The 128 device-scope atomicMin per block (1M total onto 4096 addresses,
// ~256 serialized per address) were the LAST instruction -> drain fully
// exposed at block end. Moved into the rowminF fold (before phase 2) so the
// atomic stream drains under phase-2 compute + candG write.
// Design-space ledger: 256x128 tile loses (occ 58->23%), counted-vmcnt loses
// (58->43%), dbuf-prefetch neutral, serial/atomic rowmin loses (conflicts).
__global__ __launch_bounds__(512, 4) void vq_hh(const _Float16* __restrict__ Vh,
                                                const _Float16* __restrict__ Ch,
                                                const float* __restrict__ wsv2,
                                                const float* __restrict__ wsc2,
                                                unsigned* __restrict__ candG,
                                                unsigned* __restrict__ colkey) {
  __shared__ alignas(16) _Float16 Ah[2][128 * 32];   // 16 KB (dbuf)
  __shared__ alignas(16) _Float16 Bh[2][128 * 32];   // 16 KB (dbuf)
  __shared__ float v2s[128];
  __shared__ float c2s[128];
  __shared__ float rowminW[4][128];                  // per-wn partial row mins
  __shared__ float rowminF[128];
  __shared__ unsigned cnt[128];
  __shared__ unsigned candL[128][4];
  __shared__ float colM[2][128];

  const int t = threadIdx.x;                  // 0..511
  const int lane = t & 63, w = t >> 6;        // 8 waves
  const int wm = w & 1, wn = w >> 1;          // wave grid 2x4, each 64 rows x 32 cols
  const int q = lane >> 4, c = lane & 15;
  // XCD-aware swizzle: XCD k (bid%8) gets tiles [k*1024, (k+1)*1024) ->
  // rt in [k*32, (k+1)*32): A-panel stays resident in that XCD's L2.
  const int tile = (blockIdx.x & 7) * 1024 + (blockIdx.x >> 3);
  const int rt = tile >> 5, ct = tile & 31;
  const int rowBase = rt * 128, colBase = ct * 128;

  if (t < 128)      { v2s[t] = wsv2[rowBase + t]; cnt[t] = 0u; }
  else if (t < 256) c2s[t - 128] = wsc2[colBase + (t - 128)];
  ((unsigned*)candL)[t] = 0xFFFFFFFFu;        // 512 entries, one per thread

  floatx4 acc[4][2];
  #pragma unroll
  for (int i = 0; i < 4; ++i)
    #pragma unroll
    for (int j = 0; j < 2; ++j) acc[i][j] = (floatx4){0.f, 0.f, 0.f, 0.f};

  // staging: 512 16B-chunks per operand per buffer, 1 per thread per operand.
  // XOR swizzle: slot (r, jslot) holds k-chunk jslot^((r>>1)&3) of row r.
  const int r0 = t >> 2, j0 = (t & 3) ^ ((r0 >> 1) & 3);
  const _Float16* gA = Vh + (size_t)(rowBase + r0) * DIMS + j0 * 8;
  const _Float16* gB = Ch + (size_t)(colBase + r0) * DIMS + j0 * 8;
  // wave-uniform LDS bases (wave w covers bytes [w*1024, w*1024+1024))
  char* lA = (char*)Ah + w * 1024;
  char* lB = (char*)Bh + w * 1024;
  const int sw = (c >> 1) & 3;                // frag-read swizzle term

  // prologue: stage chunk 0 into buffer 0
  glds16(gA, lA); glds16(gB, lB);
  gA += 32; gB += 32;
  __syncthreads();   // drains prologue stage + covers LDS init

  #pragma unroll
  for (int kc = 0; kc < 8; ++kc) {
    const int cur = kc & 1;
    const int nb = (cur ^ 1) * 8192;          // byte offset of the other buffer
    if (kc < 7) {                             // issue stage(k+1) FIRST
      glds16(gA, lA + nb); glds16(gB, lB + nb);
      gA += 32; gB += 32;
    }
    const _Float16* Ab = Ah[cur];
    const _Float16* Bb = Bh[cur];
    half8 a[4], b[2];
    #pragma unroll
    for (int f = 0; f < 4; ++f) {
      int ra = wm * 64 + f * 16 + c;
      a[f] = *(const half8*)(Ab + ra * 32 + (q ^ sw) * 8);
    }
    #pragma unroll
    for (int f = 0; f < 2; ++f) {
      int rb = wn * 32 + f * 16 + c;
      b[f] = *(const half8*)(Bb + rb * 32 + (q ^ sw) * 8);
    }
    #pragma unroll
    for (int fi = 0; fi < 4; ++fi)
      #pragma unroll
      for (int fj = 0; fj < 2; ++fj)
        acc[fi][fj] = __builtin_amdgcn_mfma_f32_16x16x32_f16(a[fi], b[fj], acc[fi][fj], 0, 0, 0);
    __syncthreads();
  }

  // ---- phase 1: in-place distance transform + halving rowmin + colmin -----
  float cm0 = 3.4e38f, cm1 = 3.4e38f;
  float rv[16];                               // per-lane partial row mins
  const float c2v0 = c2s[wn * 32 + c];
  const float c2v1 = c2s[wn * 32 + 16 + c];
  #pragma unroll
  for (int fi = 0; fi < 4; ++fi) {
    #pragma unroll
    for (int r = 0; r < 4; ++r) {
      int ml = wm * 64 + fi * 16 + q * 4 + r;
      float vv = v2s[ml];
      float d0 = vv + c2v0 - 2.f * acc[fi][0][r];
      float d1 = vv + c2v1 - 2.f * acc[fi][1][r];
      acc[fi][0][r] = d0;
      acc[fi][1][r] = d1;
      cm0 = fminf(cm0, d0);
      cm1 = fminf(cm1, d1);
      rv[fi * 4 + r] = fminf(d0, d1);
    }
  }
  // reduce-scatter min across the 16-lane c-group: 15 shfls, no dependencies
  // between the shfls within a step. After 4 steps lane c owns row brev4(c).
  {
    const int b0 = c & 1;
    #pragma unroll
    for (int k = 0; k < 8; ++k) {
      float send = b0 ? rv[k] : rv[k + 8];
      float recv = __shfl_xor(send, 1, 64);
      rv[k] = fminf(b0 ? rv[k + 8] : rv[k], recv);
    }
    const int b1 = (c >> 1) & 1;
    #pragma unroll
    for (int k = 0; k < 4; ++k) {
      float send = b1 ? rv[k] : rv[k + 4];
      float recv = __shfl_xor(send, 2, 64);
      rv[k] = fminf(b1 ? rv[k + 4] : rv[k], recv);
    }
    const int b2 = (c >> 2) & 1;
    #pragma unroll
    for (int k = 0; k < 2; ++k) {
      float send = b2 ? rv[k] : rv[k + 2];
      float recv = __shfl_xor(send, 4, 64);
      rv[k] = fminf(b2 ? rv[k + 2] : rv[k], recv);
    }
    const int b3 = (c >> 3) & 1;
    {
      float send = b3 ? rv[0] : rv[1];
      float recv = __shfl_xor(send, 8, 64);
      rv[0] = fminf(b3 ? rv[1] : rv[0], recv);
    }
    const int kf = (b0 << 3) | (b1 << 2) | (b2 << 1) | b3;
    rowminW[wn][wm * 64 + (kf >> 2) * 16 + q * 4 + (kf & 3)] = rv[0];
  }
  // colmin: lanes sharing a column differ only in q -> xor 16, 32
  cm0 = fminf(cm0, __shfl_xor(cm0, 16, 64));
  cm0 = fminf(cm0, __shfl_xor(cm0, 32, 64));
  cm1 = fminf(cm1, __shfl_xor(cm1, 16, 64));
  cm1 = fminf(cm1, __shfl_xor(cm1, 32, 64));
  if (lane < 16) {
    colM[wm][wn * 32 + c]      = cm0;
    colM[wm][wn * 32 + 16 + c] = cm1;
  }
  __syncthreads();

  // fold the 4 per-wn partials into the final row min, and ISSUE the colkey
  // atomics here (fire-and-forget): their serialized drain (256 atomics per
  // address device-wide) overlaps phase 2 + candG write instead of being the
  // last exposed op of the block.
  if (t < 128) {
    rowminF[t] = fminf(fminf(rowminW[0][t], rowminW[1][t]),
                       fminf(rowminW[2][t], rowminW[3][t]));
    float cv = fminf(colM[0][t], colM[1][t]);
    atomicMin(&colkey[colBase + t], __float_as_uint(cv));
  }
  __syncthreads();

  // ---- phase 2: collect candidates within rowmin + EPS_C (compare-only) ----
  #pragma unroll
  for (int fi = 0; fi < 4; ++fi) {
    #pragma unroll
    for (int r = 0; r < 4; ++r) {
      int ml = wm * 64 + fi * 16 + q * 4 + r;
      float thresh = rowminF[ml] + EPS_C;
      #pragma unroll
      for (int fj = 0; fj < 2; ++fj) {
        float d = acc[fi][fj][r];
        if (d <= thresh) {
          unsigned pos = atomicAdd(&cnt[ml], 1u);
          if (pos < 4) {
            unsigned short hb = __builtin_bit_cast(unsigned short, (_Float16)d);
            int nl = wn * 32 + fj * 16 + c;
            candL[ml][pos] = ((unsigned)hb << 16) | (unsigned)(colBase + nl);
          }
        }
      }
    }
  }
  __syncthreads();
  if (t < 128)
    *(uint4*)(candG + ((size_t)(rowBase + t) * NTILE + ct) * 4) = *(uint4*)candL[t];
}

// ---------------------------------------------------------------------------
// refine: per row pick best f16 key; fp64-verify all candidates within EPS_R
// (rare). Separate kernel: must finish reading candG (in d_out) before
// vq_gather overwrites d_out. One wave per row.
__global__ __launch_bounds__(256) void vq_refine(const float* __restrict__ V,
                                                 const float* __restrict__ CB,
                                                 const unsigned* __restrict__ candG,
                                                 unsigned* __restrict__ token) {
  int w = threadIdx.x >> 6, lane = threadIdx.x & 63;
  int row = blockIdx.x * 4 + w;
  const unsigned* cg = candG + (size_t)row * (NTILE * 4);
  unsigned e0 = cg[lane], e1 = cg[lane + 64];
  unsigned m = e0 < e1 ? e0 : e1;
  #pragma unroll
  for (int off = 1; off < 64; off <<= 1) {
    unsigned o = __shfl_xor(m, off, 64);
    m = (o < m) ? o : m;
  }
  float bestv = (float)__builtin_bit_cast(_Float16, (unsigned short)(m >> 16));
  float v0k = (float)__builtin_bit_cast(_Float16, (unsigned short)(e0 >> 16));
  float v1k = (float)__builtin_bit_cast(_Float16, (unsigned short)(e1 >> 16));
  // empty slots (0xFFFF) decode to NaN -> compare false -> excluded
  unsigned long long mask0 = __ballot(v0k <= bestv + EPS_R);
  unsigned long long mask1 = __ballot(v1k <= bestv + EPS_R);
  int tok = (int)(m & 0xFFFFu);
  if (__popcll(mask0) + __popcll(mask1) > 1) {
    float4 x = ((const float4*)(V + (size_t)row * DIMS))[lane];
    double bd = 1e300; int bi = 0x7FFFFFFF;
    #pragma unroll
    for (int h = 0; h < 2; ++h) {
      unsigned long long mask = h ? mask1 : mask0;
      unsigned ee = h ? e1 : e0;
      while (mask) {
        int l = __ffsll((unsigned long long)mask) - 1;
        mask &= mask - 1;
        int idx = (int)(__shfl(ee, l, 64) & 0xFFFFu);
        float4 cv = ((const float4*)(CB + (size_t)idx * DIMS))[lane];
        double dx = (double)cv.x - (double)x.x;
        double dy = (double)cv.y - (double)x.y;
        double dz = (double)cv.z - (double)x.z;
        double dw = (double)cv.w - (double)x.w;
        double s = dx * dx + dy * dy + dz * dz + dw * dw;
        #pragma unroll
        for (int off = 1; off < 64; off <<= 1) s += __shfl_xor(s, off, 64);
        if (s < bd || (s == bd && idx < bi)) { bd = s; bi = idx; }
      }
    }
    tok = bi;
  }
  if (lane == 0) token[row] = (unsigned)tok;
}

// ---------------------------------------------------------------------------
// gather: out = x + (e - x); per-block mse partial via PLAIN STORE (round 4's
// __threadfence per block forced an L2 wb/inv per block -> 268 us stall).
// v12: nontemporal store via clang ext_vector (floatx4) — HIP's float4 struct
// is rejected by __builtin_nontemporal_store (round-11 compile error).
__global__ __launch_bounds__(256) void vq_gather(const float* __restrict__ V,
                                                 const float* __restrict__ CB,
                                                 const unsigned* __restrict__ token,
                                                 float* __restrict__ ws,
                                                 float* __restrict__ out) {
  __shared__ float psum[4];
  int w = threadIdx.x >> 6, lane = threadIdx.x & 63;
  int row = blockIdx.x * 4 + w;
  int tok = (int)token[row];

  float4 e = *(const float4*)(CB + (size_t)tok * DIMS + lane * 4);
  float4 x = *(const float4*)(V + (size_t)row * DIMS + lane * 4);
  float dx = e.x - x.x, dy = e.y - x.y, dz = e.z - x.z, dw = e.w - x.w;
  floatx4 o;
  o[0] = x.x + dx; o[1] = x.y + dy; o[2] = x.z + dz; o[3] = x.w + dw;
  __builtin_nontemporal_store(o, (floatx4*)(out + (size_t)row * DIMS + lane * 4));

  float s = dx * dx + dy * dy + dz * dz + dw * dw;
  #pragma unroll
  for (int off = 32; off > 0; off >>= 1) s += __shfl_down(s, off, 64);
  if (lane == 0) psum[w] = s;
  __syncthreads();
  if (threadIdx.x == 0)
    ws[WS_PART + blockIdx.x] = psum[0] + psum[1] + psum[2] + psum[3];
}

// ---------------------------------------------------------------------------
// final: sum 8192 mse partials + 4096 colmins, write loss. One block.
// v11: 1024 threads (16 waves) — at 256 threads this latency-bound serial
// tail did ~48 dependent-ish HBM loads/thread with only 4 waves to hide them.
__global__ __launch_bounds__(1024) void vq_final(const float* __restrict__ ws,
                                                 float* __restrict__ out) {
  __shared__ float psum[16];
  float s = 0.f;
  for (int i = threadIdx.x; i < 8192; i += 1024) s += ws[WS_PART + i];
  const unsigned* ck = (const unsigned*)(ws + WS_COLKEY);
  float cs = 0.f;
  for (int i = threadIdx.x; i < KCODES; i += 1024) cs += __uint_as_float(ck[i]);
  float v = s * (1.25f / 8388608.f) + cs * (0.1f / 4096.f);
  #pragma unroll
  for (int off = 32; off > 0; off >>= 1) v += __shfl_down(v, off, 64);
  int w = threadIdx.x >> 6, lane = threadIdx.x & 63;
  if (lane == 0) psum[w] = v;
  __syncthreads();
  if (threadIdx.x == 0) {
    float acc = 0.f;
    #pragma unroll
    for (int i = 0; i < 16; ++i) acc += psum[i];
    out[8388608] = acc;
  }
}

// ---------------------------------------------------------------------------
extern "C" void kernel_launch(void* const* d_in, const int* in_sizes, int n_in,
                              void* d_out, int out_size, void* d_ws, size_t ws_size,
                              hipStream_t stream) {
  const float* V  = (const float*)d_in[0];   // [32768, 256]
  const float* CB = (const float*)d_in[1];   // [4096, 256]
  float* out = (float*)d_out;                // 8388608 emb + 1 loss
  float* ws  = (float*)d_ws;

  _Float16* Vh     = (_Float16*)out;                 // scratch in d_out
  unsigned* candG  = (unsigned*)(out + 4194304);     // scratch in d_out (16 MB)
  unsigned* colkey = (unsigned*)(ws + WS_COLKEY);
  unsigned* token  = (unsigned*)(ws + WS_TOKEN);

  vq_prep<<<(M_ROWS + KCODES) / 4, 256, 0, stream>>>(V, CB, ws, out);
  vq_hh<<<8192, 512, 0, stream>>>(Vh, (const _Float16*)(ws + WS_CH),
                                  ws + WS_V2, ws + WS_C2, candG, colkey);
  vq_refine<<<M_ROWS / 4, 256, 0, stream>>>(V, CB, candG, token);
  vq_gather<<<M_ROWS / 4, 256, 0, stream>>>(V, CB, token, ws, out);
  vq_final<<<1, 1024, 0, stream>>>(ws, out);
}